// Round 16
// baseline (92.497 us; speedup 1.0000x reference)
//
#include <hip/hip_runtime.h>
#include <cstdint>
#include <cstddef>

// Problem constants: B=4, C=256, H=60, W=80, N=4800
#define BQ 4
#define CDIM 256
#define HH 60
#define WW 80
#define NP 4800
#define NPAD 4864          // 76*64 = 38*128
#define BT 128             // tile rows (t, A = tar)
#define BJ 64              // tile cols (j, B = ref)
#define NTT 38             // t tiles (128)
#define NTJ 76             // j tiles (64)
#define NBLK (BQ * NTJ * NTT)   // 11552, %8==0
#define NLB 600            // k_loss blocks per batch (8 points each)

typedef float f32x4 __attribute__((ext_vector_type(4)));
typedef float f32x16 __attribute__((ext_vector_type(16)));
typedef int i32x4 __attribute__((ext_vector_type(4)));
typedef int i32x8 __attribute__((ext_vector_type(8)));
typedef unsigned short u16x8 __attribute__((ext_vector_type(8)));
typedef unsigned char u8x8 __attribute__((ext_vector_type(8)));

// ---------------- ws layout (bytes) ----------------
#define WS_DEST 0              // bf16 2*4*4800*256*2 = 19,660,800 (dead after k_sample)
#define WS_PART 0              // uint2 4*4800*38*8 = 5,836,800 (aliases desT)
#define WS_REFB 19660800       // bf16 4*4864*256*2 = 9,961,472 (for k_loss)
#define WS_TARB 29622272       // bf16                9,961,472
#define WS_REFQ 39583744       // fp8 4*4864*256 = 4,980,736 (for GEMM, plain k layout)
#define WS_TARQ 44564480       // fp8                4,980,736
#define WS_BPART 49545216      // float2 4*600 = 19,200 B (k_loss block partials)
// end 49,564,416

#define GLD16(dst, src) __builtin_amdgcn_global_load_lds( \
    (const __attribute__((address_space(1))) void*)(src), \
    (__attribute__((address_space(3))) void*)(dst), 16, 0, 0)

__device__ inline unsigned short f2bf(float f) {
  unsigned int u = __float_as_uint(f);
  return (unsigned short)((u + 0x7FFFu + ((u >> 16) & 1u)) >> 16);  // RNE
}
__device__ inline float bf2f(unsigned short s) {
  return __uint_as_float((unsigned int)s << 16);
}
// f32 -> OCP e4m3fn, RNE, clamp to +-448, subnormals handled
__device__ inline unsigned char f2e4m3(float x) {
  float ax = fminf(fabsf(x), 448.f);
  const unsigned int sign = (__float_as_uint(x) >> 24) & 0x80u;
  if (ax < 0.015625f) {                     // below 2^-6: subnormal (or carry to 0x08)
    const int M = (int)rintf(ax * 512.f);   // 0..8; 8 == 2^-6 encodes as E=1,M=0
    return (unsigned char)(sign | (unsigned int)M);
  }
  unsigned int u = __float_as_uint(ax);
  u += 0x7FFFFu + ((u >> 20) & 1u);         // RNE at mantissa bit 20 (carry ok)
  unsigned int e = (u >> 23) - 120u;        // exp bias 127 -> 7
  unsigned int m = (u >> 20) & 7u;
  if (e >= 16u) { e = 15u; m = 6u; }        // clamp to 448 (rounding overshoot)
  return (unsigned char)(sign | (e << 3) | m);
}

// ---------------- transpose des (C, HW) f32 -> (HW, C) bf16 ----------------
__global__ __launch_bounds__(256)
void k_transpose(const float* __restrict__ src, const float* __restrict__ tgt,
                 unsigned short* __restrict__ desT) {
  __shared__ float tile[64][33];
  const int z = blockIdx.z;  // tensor*4 + b
  const float* in = ((z >> 2) ? tgt : src) + (size_t)(z & 3) * CDIM * NP;
  unsigned short* out = desT + (size_t)z * NP * CDIM;
  const int hw0 = blockIdx.x * 32;
  const int c0 = blockIdx.y * 64;
  const int tx = threadIdx.x, ty = threadIdx.y;
#pragma unroll
  for (int q = 0; q < 8; ++q)
    tile[ty + q * 8][tx] = in[(size_t)(c0 + ty + q * 8) * NP + hw0 + tx];
  __syncthreads();
  const int lt = ty * 32 + tx;
  const int c2 = lt & 7;        // 8 channels each
  const int hw = lt >> 3;       // 0..31
  u16x8 o;
#pragma unroll
  for (int k = 0; k < 8; ++k) o[k] = f2bf(tile[c2 * 8 + k][hw]);
  *(u16x8*)(out + (size_t)(hw0 + hw) * CDIM + c0 + c2 * 8) = o;
}

// ---------------- bilinear sample + L2 normalize: 32 lanes/point, 16B reads ----------------
__global__ __launch_bounds__(256)
void k_sample(const unsigned short* __restrict__ desT,
              const float* __restrict__ spts, const float* __restrict__ tpts,
              unsigned short* __restrict__ refB, unsigned short* __restrict__ tarB,
              unsigned char* __restrict__ refQ, unsigned char* __restrict__ tarQ) {
  const int pg = threadIdx.x >> 5, l = threadIdx.x & 31;
  const int n = blockIdx.x * 8 + pg;        // 0..NPAD-1
  const int b = blockIdx.y;
  const int tensor = blockIdx.z;            // 0: ref, 1: tar
  unsigned short* outRowB = (tensor ? tarB : refB) + ((size_t)b * NPAD + n) * CDIM;
  unsigned char*  outRowQ = (tensor ? tarQ : refQ) + ((size_t)b * NPAD + n) * CDIM;
  const int c0 = l * 8;
  if (n >= NP) {  // zero pad rows (uniform per 32-group)
    *(u16x8*)(outRowB + c0) = (u16x8){0, 0, 0, 0, 0, 0, 0, 0};
    *(u8x8*)(outRowQ + c0) = (u8x8){0, 0, 0, 0, 0, 0, 0, 0};
    return;
  }
  const float* pts = (tensor ? tpts : spts) + ((size_t)b * NP + n) * 2;
  const float gx = pts[0], gy = pts[1];
  const float x = (gx + 1.f) * ((WW - 1) * 0.5f);
  const float y = (gy + 1.f) * ((HH - 1) * 0.5f);
  float x0f = fminf(fmaxf(floorf(x), 0.f), (float)(WW - 1));
  float y0f = fminf(fmaxf(floorf(y), 0.f), (float)(HH - 1));
  float x1f = fminf(x0f + 1.f, (float)(WW - 1));
  float y1f = fminf(y0f + 1.f, (float)(HH - 1));
  const float wx = x - x0f, wy = y - y0f;
  const int ix0 = (int)x0f, ix1 = (int)x1f, iy0 = (int)y0f, iy1 = (int)y1f;
  const unsigned short* base = desT + (size_t)(tensor * 4 + b) * NP * CDIM + c0;
  const u16x8 u00 = *(const u16x8*)(base + (size_t)(iy0 * WW + ix0) * CDIM);
  const u16x8 u01 = *(const u16x8*)(base + (size_t)(iy0 * WW + ix1) * CDIM);
  const u16x8 u10 = *(const u16x8*)(base + (size_t)(iy1 * WW + ix0) * CDIM);
  const u16x8 u11 = *(const u16x8*)(base + (size_t)(iy1 * WW + ix1) * CDIM);
  const float w00 = (1.f - wx) * (1.f - wy), w01 = wx * (1.f - wy);
  const float w10 = (1.f - wx) * wy,         w11 = wx * wy;
  float v[8];
  float sum = 0.f;
#pragma unroll
  for (int k = 0; k < 8; ++k) {
    v[k] = bf2f(u00[k]) * w00 + bf2f(u01[k]) * w01 + bf2f(u10[k]) * w10 + bf2f(u11[k]) * w11;
    const float s = v[k] + 1e-8f;
    sum += s * s;
  }
#pragma unroll
  for (int d = 1; d < 32; d <<= 1) sum += __shfl_xor(sum, d);  // stays in 32-group
  const float inv = 1.f / (sqrtf(sum) + 1e-8f);
  const float invq = inv * 16.f;   // scale into e4m3 normal range; dot' = 256*dot
  u16x8 ob;
  u8x8 oq;
#pragma unroll
  for (int k = 0; k < 8; ++k) {
    ob[k] = f2bf(v[k] * inv);
    oq[k] = f2e4m3(v[k] * invq);
  }
  *(u16x8*)(outRowB + c0) = ob;
  *(u8x8*)(outRowQ + c0) = oq;
}

// ---------------- MX-fp8 MFMA GEMM (128t x 64j, 32x32x64, unit scales) + dual argmax ----------------
// Round-16: halve the wave tile to 64t x 32j -> acc = 32 AGPR (was 64); est ~92
// regs/wave -> launch_bounds (256,5) = 5 blocks/CU, 20 waves (was 4/16). Round-15's
// VALU idle (37%) was barrier/memory wait; more independent barrier groups fill it
// (round-10 mechanism). Per-wave work halves, block count doubles (11552) - total
// identical. Proven staging/swizzle carries over: stored slot s of row r holds
// s ^ ((r>>1)&3) ^ ((r>>4)&3); A reads add (fa<<1), B reads (wc<<1) (row bits 4-5).
// partial layout (NTT=38) unchanged -> k_loss untouched structurally.
// Tripwire: FETCH >> 8 MB means (256,5) forced a spill -> revert.
struct Smem {
  char bufs[2][12288];   // per buf: A [128][64B] @0, B [64][64B] @8192
  float2 tc2[128];       // t coords (x,y)
  float2 jc2[64];        // j coords (x,y)
};                       // 26,112 B -> 5 blocks/CU (LDS would allow 6; VGPR caps 5)

__global__ __launch_bounds__(256, 5)
void k_mfma_argmax(const unsigned char* __restrict__ tarQ,
                   const unsigned char* __restrict__ refQ,
                   const float* __restrict__ un, const int* __restrict__ relax,
                   uint2* __restrict__ partial) {
  __shared__ Smem sm;
  const int tid = threadIdx.x;
  const int lane = tid & 63;
  const int wid = tid >> 6;

  // XCD swizzle (11552 % 8 == 0)
  const int bid = blockIdx.x;
  const int item = (bid & 7) * (NBLK / 8) + (bid >> 3);
  const int b = item / (NTJ * NTT);
  const int r2 = item - b * (NTJ * NTT);
  const int jt = r2 / NTT, tt = r2 % NTT;
  const int tbase = tt * BT, jbase = jt * BJ;
  const float* unb = un + (size_t)b * 2 * NP;

  // stage coords into LDS (before first barrier)
  if (tid < 128) {
    const int tg = (tbase + tid < NP) ? tbase + tid : NP - 1;
    sm.tc2[tid] = make_float2(unb[tg], unb[NP + tg]);
  } else if (tid < 192) {
    const int i2 = tid - 128;
    const int jg = (jbase + i2 < NP) ? jbase + i2 : NP - 1;
    sm.jc2[i2] = make_float2(unb[jg], unb[NP + jg]);
  }

  // staging: waves 0-1 -> A (64 rows each, 4 GLD/kb), waves 2-3 -> B (32 rows each, 2 GLD/kb)
  // global rows are 256 B (fp8, plain k); kb selects a 64-B slice.
  // Stored slot of row r = s ^ ((r>>1)&3) ^ ((r>>4)&3); (r>>1)&3 = (lane>>3)&3 for
  // r = base + (lane>>2); (r>>4)&3 = qq for A, ((wid-2)<<1)^qq for B (folded into srcSwz).
  const char* aSrc = (const char*)(tarQ + ((size_t)b * NPAD + tbase) * CDIM);
  const char* bSrc = (const char*)(refQ + ((size_t)b * NPAD + jbase) * CDIM);
  const char* gl; int ldsOff, nq;
  if (wid < 2) {
    gl = aSrc + (size_t)(wid * 64 + (lane >> 2)) * 256;
    ldsOff = wid * 4096; nq = 4;
  } else {
    gl = bSrc + (size_t)((wid - 2) * 32 + (lane >> 2)) * 256;
    ldsOff = 8192 + (wid - 2) * 2048; nq = 2;
  }
  const int srcSwz = (lane & 3) ^ ((lane >> 3) & 3) ^ (wid < 2 ? 0 : ((wid - 2) << 1));

#define STAGE(buf, kb) do { \
    char* ldst = sm.bufs[buf] + ldsOff; \
    const char* gsp = gl + (kb) * 64; \
    _Pragma("unroll") for (int qq = 0; qq < 4; ++qq) \
      if (qq < nq) GLD16(ldst + qq * 1024, gsp + (size_t)qq * 4096 + ((srcSwz ^ qq) * 16)); \
  } while (0)

  const int wr = wid >> 1, wc = wid & 1;   // wave tile: 64t x 32j
  const int l31 = lane & 31, kg = lane >> 5;
  const int swm = ((l31 >> 1) & 3) ^ ((l31 >> 4) & 1);   // read-side slot swizzle (row bits 1-2, 4)
  const int bswm = swm ^ (wc << 1);                       // B adds row bit 5 = wc

  f32x16 acc[2];
#pragma unroll
  for (int fa = 0; fa < 2; ++fa)
#pragma unroll
    for (int r = 0; r < 16; ++r) acc[fa][r] = 0.f;

  // loop-invariant LDS read bases
  const char* aptr = sm.bufs[0] + (wr * 64 + l31) * 64;
  const char* bptr = sm.bufs[0] + 8192 + (wc * 32 + l31) * 64;

  STAGE(0, 0);
  __syncthreads();
#pragma unroll
  for (int kb = 0; kb < 4; ++kb) {   // K = 256 = 4 * 64
    const int bo = (kb & 1) * 12288;
    if (kb < 3) STAGE((kb & 1) ^ 1, kb + 1);   // issue next-tile loads before compute
    i32x8 aF[2], bF;
#pragma unroll
    for (int fa = 0; fa < 2; ++fa) {           // A row = wr*64 + fa*32 + l31
      const int sx0 = (((2 * kg) ^ swm ^ (fa << 1)) << 4);
      const int sx1 = (((2 * kg + 1) ^ swm ^ (fa << 1)) << 4);
      const i32x4 alo = *(const i32x4*)(aptr + bo + fa * 2048 + sx0);
      const i32x4 ahi = *(const i32x4*)(aptr + bo + fa * 2048 + sx1);
      aF[fa] = __builtin_shufflevector(alo, ahi, 0, 1, 2, 3, 4, 5, 6, 7);
    }
    {                                          // B row = wc*32 + l31
      const int sx0 = (((2 * kg) ^ bswm) << 4);
      const int sx1 = (((2 * kg + 1) ^ bswm) << 4);
      const i32x4 blo = *(const i32x4*)(bptr + bo + sx0);
      const i32x4 bhi = *(const i32x4*)(bptr + bo + sx1);
      bF = __builtin_shufflevector(blo, bhi, 0, 1, 2, 3, 4, 5, 6, 7);
    }
    __builtin_amdgcn_s_setprio(1);
#pragma unroll
    for (int fa = 0; fa < 2; ++fa)
      acc[fa] = __builtin_amdgcn_mfma_scale_f32_32x32x64_f8f6f4(
          aF[fa], bF, acc[fa], 0, 0,
          0, 0x7F7F7F7F, 0, 0x7F7F7F7F);   // fmt fp8/fp8, scales = 1.0
    __builtin_amdgcn_s_setprio(0);
    if (kb < 3) __syncthreads();   // kb3: no LDS reuse below (red is in bufs[0], reads ended kb2)
  }

  // ---- epilogue: packed-key dual argmax (u32: [31:13]=bits(acc+512), [12:0]=8191-t) ----
  // 32x32 C/D map: col j = wc*32 + l31; row t = wr*64 + fa*32 + 4*kg + (reg&3) + 8*(reg>>2)
  const float rf = (float)relax[0];
  const float2 jj = sm.jc2[wc * 32 + l31];
  const float jx = jj.x, jy = jj.y;
  unsigned int kA = 0u, kI = 0u;
  const unsigned int tinv0 = (unsigned int)(8191 - tbase);

#define EPILOG(TAIL) \
  _Pragma("unroll") for (int fa = 0; fa < 2; ++fa) { \
    _Pragma("unroll") for (int reg = 0; reg < 16; ++reg) { \
      const int tl = wr * 64 + fa * 32 + 4 * kg + (reg & 3) + 8 * (reg >> 2); \
      const float2 tj = sm.tc2[tl]; \
      const unsigned int tinv = tinv0 - tl; \
      unsigned int key = (__float_as_uint(acc[fa][reg] + 512.f) & 0xFFFFE000u) | tinv; \
      if (TAIL && (tbase + tl >= NP)) key = 0u; \
      if (key > kA) kA = key; \
      const float mm = fmaxf(fabsf(tj.x - jx), fabsf(tj.y - jy)); \
      const unsigned int keyI = (mm <= rf) ? 0u : key; \
      if (keyI > kI) kI = keyI; \
    } \
  }

  if (tbase + BT <= NP) { EPILOG(false) } else { EPILOG(true) }
#undef EPILOG

  // cross-lane reduce: lanes l and l^32 share j (disjoint t) -> one shfl step.
  uint2* red = (uint2*)sm.bufs[0];   // [2][64]; safe: bufs[0] reads ended at kb=2 barrier
  {
    const unsigned int oA = __shfl_xor(kA, 32);
    const unsigned int oI = __shfl_xor(kI, 32);
    if (oA > kA) kA = oA;
    if (oI > kI) kI = oI;
    if (kg == 0) red[wr * 64 + wc * 32 + l31] = make_uint2(kA, kI);
  }
  __syncthreads();
  if (tid < 64) {
    const int jg = jbase + tid;
    if (jg < NP) {
      uint2 p0 = red[tid];
      const uint2 p1 = red[64 + tid];
      if (p1.x > p0.x) p0.x = p1.x;
      if (p1.y > p0.y) p0.y = p1.y;
      partial[((size_t)b * NP + jg) * NTT + tt] = p0;
    }
  }
#undef STAGE
}

// ---------------- fused combine + loss + recall: 2 points/wave, block partials ----------------
// Round-16 FIX: NTT=38 > 32 lanes — each lane must also cover partial l+32 (rounds
// 14-15 silently dropped t-tiles 32-37; passed only inside tolerance).
__global__ __launch_bounds__(256)
void k_loss(const unsigned short* __restrict__ refB, const unsigned short* __restrict__ tarB,
            const float* __restrict__ un, const uint2* __restrict__ partial,
            float2* __restrict__ blockpart) {
  const int pg = threadIdx.x >> 5, l = threadIdx.x & 31;
  const int n = blockIdx.x * 8 + pg;
  const int b = blockIdx.y;
  const int bn = b * NP + n;
  unsigned int kA = 0u, kI = 0u;
  {
    const uint2 p = partial[(size_t)bn * NTT + l];          // l < 32 <= NTT
    kA = p.x; kI = p.y;
    if (l + 32 < NTT) {
      const uint2 q = partial[(size_t)bn * NTT + l + 32];
      if (q.x > kA) kA = q.x;
      if (q.y > kI) kI = q.y;
    }
  }
#pragma unroll
  for (int d = 1; d < 32; d <<= 1) {   // stays within the 32-lane group
    const unsigned int oA = __shfl_xor(kA, d);
    const unsigned int oI = __shfl_xor(kI, d);
    if (oA > kA) kA = oA;
    if (oI > kI) kI = oI;
  }
  const int nn  = 8191 - (int)(kA & 0x1FFFu);
  const int neg = 8191 - (int)(kI & 0x1FFFu);
  const int c0 = l * 8;
  const u16x8 rv = *(const u16x8*)(refB + ((size_t)b * NPAD + n) * CDIM + c0);
  const u16x8 tv = *(const u16x8*)(tarB + ((size_t)b * NPAD + n) * CDIM + c0);
  const u16x8 gv = *(const u16x8*)(tarB + ((size_t)b * NPAD + neg) * CDIM + c0);
  float dp = 0.f, dn = 0.f;
#pragma unroll
  for (int k = 0; k < 8; ++k) {
    const float r = bf2f(rv[k]);
    float d1 = r - bf2f(tv[k]) + 1e-6f;
    float d2 = r - bf2f(gv[k]) + 1e-6f;
    dp += d1 * d1;
    dn += d2 * d2;
  }
#pragma unroll
  for (int off = 1; off < 32; off <<= 1) {
    dp += __shfl_xor(dp, off);
    dn += __shfl_xor(dn, off);
  }
  __shared__ float2 sred[8];
  if (l == 0) {
    const float loss = fmaxf(sqrtf(dp) - sqrtf(dn) + 0.2f, 0.f);
    const float* unb = un + (size_t)b * 2 * NP;
    const float rec = (unb[nn] == unb[n] && unb[NP + nn] == unb[NP + n]) ? 1.f : 0.f;
    sred[pg] = make_float2(loss, rec);
  }
  __syncthreads();
  if (threadIdx.x == 0) {
    float sl = 0.f, sr = 0.f;
#pragma unroll
    for (int g = 0; g < 8; ++g) { sl += sred[g].x; sr += sred[g].y; }
    blockpart[b * NLB + blockIdx.x] = make_float2(sl, sr);
  }
}

// ---------------- final deterministic reduce (19.2 KB input) ----------------
__global__ __launch_bounds__(256)
void k_finalize(const float2* __restrict__ blockpart, float* __restrict__ out) {
  __shared__ float l[256], rr[256];
  float ls = 0.f, rs = 0.f;
  for (int i = threadIdx.x; i < BQ * NLB; i += 256) {
    const float2 p = blockpart[i];
    ls += p.x; rs += p.y;
  }
  l[threadIdx.x] = ls;
  rr[threadIdx.x] = rs;
  __syncthreads();
  for (int s = 128; s > 0; s >>= 1) {
    if (threadIdx.x < s) { l[threadIdx.x] += l[threadIdx.x + s]; rr[threadIdx.x] += rr[threadIdx.x + s]; }
    __syncthreads();
  }
  if (threadIdx.x == 0) {
    out[0] = l[0] / (float)(BQ * NP);
    out[1] = rr[0] / (float)(BQ * NP);
  }
}

extern "C" void kernel_launch(void* const* d_in, const int* in_sizes, int n_in,
                              void* d_out, int out_size, void* d_ws, size_t ws_size,
                              hipStream_t stream) {
  const float* src  = (const float*)d_in[0];
  const float* tgt  = (const float*)d_in[1];
  const float* spts = (const float*)d_in[2];
  const float* tpts = (const float*)d_in[3];
  const float* un   = (const float*)d_in[4];
  const int* relax  = (const int*)d_in[5];

  char* ws = (char*)d_ws;
  unsigned short* desT      = (unsigned short*)(ws + WS_DEST);
  uint2*          partial   = (uint2*)(ws + WS_PART);   // aliases desT (dead by then)
  unsigned short* refB      = (unsigned short*)(ws + WS_REFB);
  unsigned short* tarB      = (unsigned short*)(ws + WS_TARB);
  unsigned char*  refQ      = (unsigned char*)(ws + WS_REFQ);
  unsigned char*  tarQ      = (unsigned char*)(ws + WS_TARQ);
  float2*         blockpart = (float2*)(ws + WS_BPART);
  float*          out       = (float*)d_out;

  k_transpose<<<dim3(NP / 32, CDIM / 64, 8), dim3(32, 8), 0, stream>>>(src, tgt, desT);
  k_sample<<<dim3(NPAD / 8, BQ, 2), 256, 0, stream>>>(desT, spts, tpts, refB, tarB, refQ, tarQ);
  k_mfma_argmax<<<NBLK, 256, 0, stream>>>(tarQ, refQ, un, relax, partial);
  k_loss<<<dim3(NLB, BQ), 256, 0, stream>>>(refB, tarB, un, partial, blockpart);
  k_finalize<<<1, 256, 0, stream>>>(blockpart, out);
}

// Round 17
// 84.105 us; speedup vs baseline: 1.0998x; 1.0998x over previous
//
#include <hip/hip_runtime.h>
#include <cstdint>
#include <cstddef>

// Problem constants: B=4, C=256, H=60, W=80, N=4800
#define BQ 4
#define CDIM 256
#define HH 60
#define WW 80
#define NP 4800
#define NPAD 4864          // 38*128
#define BT 128             // tile rows (t, A = tar)
#define BJ 128             // tile cols (j, B = ref)
#define NTT 38             // t tiles (128)
#define NTJ 38             // j tiles (128)
#define NBLK (BQ * NTJ * NTT)   // 5776, %8==0
#define NLB 600            // k_loss blocks per batch (8 points each)

typedef float f32x4 __attribute__((ext_vector_type(4)));
typedef float f32x16 __attribute__((ext_vector_type(16)));
typedef int i32x4 __attribute__((ext_vector_type(4)));
typedef int i32x8 __attribute__((ext_vector_type(8)));
typedef unsigned short u16x8 __attribute__((ext_vector_type(8)));
typedef unsigned char u8x8 __attribute__((ext_vector_type(8)));

// ---------------- ws layout (bytes) ----------------
#define WS_DEST 0              // bf16 2*4*4800*256*2 = 19,660,800 (dead after k_sample)
#define WS_PART 0              // uint2 4*4800*38*8 = 5,836,800 (aliases desT)
#define WS_REFB 19660800       // bf16 4*4864*256*2 = 9,961,472 (for k_loss)
#define WS_TARB 29622272       // bf16                9,961,472
#define WS_REFQ 39583744       // fp8 4*4864*256 = 4,980,736 (for GEMM, plain k layout)
#define WS_TARQ 44564480       // fp8                4,980,736
#define WS_BPART 49545216      // float2 4*600 = 19,200 B (k_loss block partials)
// end 49,564,416

#define GLD16(dst, src) __builtin_amdgcn_global_load_lds( \
    (const __attribute__((address_space(1))) void*)(src), \
    (__attribute__((address_space(3))) void*)(dst), 16, 0, 0)

__device__ inline unsigned short f2bf(float f) {
  unsigned int u = __float_as_uint(f);
  return (unsigned short)((u + 0x7FFFu + ((u >> 16) & 1u)) >> 16);  // RNE
}
__device__ inline float bf2f(unsigned short s) {
  return __uint_as_float((unsigned int)s << 16);
}
// f32 -> OCP e4m3fn, RNE, clamp to +-448, subnormals handled
__device__ inline unsigned char f2e4m3(float x) {
  float ax = fminf(fabsf(x), 448.f);
  const unsigned int sign = (__float_as_uint(x) >> 24) & 0x80u;
  if (ax < 0.015625f) {                     // below 2^-6: subnormal (or carry to 0x08)
    const int M = (int)rintf(ax * 512.f);   // 0..8; 8 == 2^-6 encodes as E=1,M=0
    return (unsigned char)(sign | (unsigned int)M);
  }
  unsigned int u = __float_as_uint(ax);
  u += 0x7FFFFu + ((u >> 20) & 1u);         // RNE at mantissa bit 20 (carry ok)
  unsigned int e = (u >> 23) - 120u;        // exp bias 127 -> 7
  unsigned int m = (u >> 20) & 7u;
  if (e >= 16u) { e = 15u; m = 6u; }        // clamp to 448 (rounding overshoot)
  return (unsigned char)(sign | (e << 3) | m);
}

// ---------------- transpose des (C, HW) f32 -> (HW, C) bf16 ----------------
__global__ __launch_bounds__(256)
void k_transpose(const float* __restrict__ src, const float* __restrict__ tgt,
                 unsigned short* __restrict__ desT) {
  __shared__ float tile[64][33];
  const int z = blockIdx.z;  // tensor*4 + b
  const float* in = ((z >> 2) ? tgt : src) + (size_t)(z & 3) * CDIM * NP;
  unsigned short* out = desT + (size_t)z * NP * CDIM;
  const int hw0 = blockIdx.x * 32;
  const int c0 = blockIdx.y * 64;
  const int tx = threadIdx.x, ty = threadIdx.y;
#pragma unroll
  for (int q = 0; q < 8; ++q)
    tile[ty + q * 8][tx] = in[(size_t)(c0 + ty + q * 8) * NP + hw0 + tx];
  __syncthreads();
  const int lt = ty * 32 + tx;
  const int c2 = lt & 7;        // 8 channels each
  const int hw = lt >> 3;       // 0..31
  u16x8 o;
#pragma unroll
  for (int k = 0; k < 8; ++k) o[k] = f2bf(tile[c2 * 8 + k][hw]);
  *(u16x8*)(out + (size_t)(hw0 + hw) * CDIM + c0 + c2 * 8) = o;
}

// ---------------- bilinear sample + L2 normalize: 32 lanes/point, 16B reads ----------------
__global__ __launch_bounds__(256)
void k_sample(const unsigned short* __restrict__ desT,
              const float* __restrict__ spts, const float* __restrict__ tpts,
              unsigned short* __restrict__ refB, unsigned short* __restrict__ tarB,
              unsigned char* __restrict__ refQ, unsigned char* __restrict__ tarQ) {
  const int pg = threadIdx.x >> 5, l = threadIdx.x & 31;
  const int n = blockIdx.x * 8 + pg;        // 0..NPAD-1
  const int b = blockIdx.y;
  const int tensor = blockIdx.z;            // 0: ref, 1: tar
  unsigned short* outRowB = (tensor ? tarB : refB) + ((size_t)b * NPAD + n) * CDIM;
  unsigned char*  outRowQ = (tensor ? tarQ : refQ) + ((size_t)b * NPAD + n) * CDIM;
  const int c0 = l * 8;
  if (n >= NP) {  // zero pad rows (uniform per 32-group)
    *(u16x8*)(outRowB + c0) = (u16x8){0, 0, 0, 0, 0, 0, 0, 0};
    *(u8x8*)(outRowQ + c0) = (u8x8){0, 0, 0, 0, 0, 0, 0, 0};
    return;
  }
  const float* pts = (tensor ? tpts : spts) + ((size_t)b * NP + n) * 2;
  const float gx = pts[0], gy = pts[1];
  const float x = (gx + 1.f) * ((WW - 1) * 0.5f);
  const float y = (gy + 1.f) * ((HH - 1) * 0.5f);
  float x0f = fminf(fmaxf(floorf(x), 0.f), (float)(WW - 1));
  float y0f = fminf(fmaxf(floorf(y), 0.f), (float)(HH - 1));
  float x1f = fminf(x0f + 1.f, (float)(WW - 1));
  float y1f = fminf(y0f + 1.f, (float)(HH - 1));
  const float wx = x - x0f, wy = y - y0f;
  const int ix0 = (int)x0f, ix1 = (int)x1f, iy0 = (int)y0f, iy1 = (int)y1f;
  const unsigned short* base = desT + (size_t)(tensor * 4 + b) * NP * CDIM + c0;
  const u16x8 u00 = *(const u16x8*)(base + (size_t)(iy0 * WW + ix0) * CDIM);
  const u16x8 u01 = *(const u16x8*)(base + (size_t)(iy0 * WW + ix1) * CDIM);
  const u16x8 u10 = *(const u16x8*)(base + (size_t)(iy1 * WW + ix0) * CDIM);
  const u16x8 u11 = *(const u16x8*)(base + (size_t)(iy1 * WW + ix1) * CDIM);
  const float w00 = (1.f - wx) * (1.f - wy), w01 = wx * (1.f - wy);
  const float w10 = (1.f - wx) * wy,         w11 = wx * wy;
  float v[8];
  float sum = 0.f;
#pragma unroll
  for (int k = 0; k < 8; ++k) {
    v[k] = bf2f(u00[k]) * w00 + bf2f(u01[k]) * w01 + bf2f(u10[k]) * w10 + bf2f(u11[k]) * w11;
    const float s = v[k] + 1e-8f;
    sum += s * s;
  }
#pragma unroll
  for (int d = 1; d < 32; d <<= 1) sum += __shfl_xor(sum, d);  // stays in 32-group
  const float inv = 1.f / (sqrtf(sum) + 1e-8f);
  const float invq = inv * 16.f;   // scale into e4m3 normal range; dot' = 256*dot
  u16x8 ob;
  u8x8 oq;
#pragma unroll
  for (int k = 0; k < 8; ++k) {
    ob[k] = f2bf(v[k] * inv);
    oq[k] = f2e4m3(v[k] * invq);
  }
  *(u16x8*)(outRowB + c0) = ob;
  *(u8x8*)(outRowQ + c0) = oq;
}

// ---------------- MX-fp8 MFMA GEMM (128t x 128j, 32x32x64, unit scales) + dual argmax ----------------
// ROUND-15 CONFIGURATION RESTORED VERBATIM (proven 45.4 us, conflicts 92K).
// Round-16's 128x64 tile raised occupancy (42%) but cost 1.5x staging instructions +
// 2x per-block fixed VALU (A-panel amortized over half the output): 55 us. Reverted.
// Extended swizzle: stored slot s of row r holds s ^ ((r>>1)&3) ^ ((r>>4)&3);
// read side adds (f<<1) for row bit 5. Only the free 2-way (l, l+8) alias remains.
struct Smem {
  char bufs[2][16384];   // per buf: A [128][64B] @0, B [128][64B] @8192
  float2 tc2[128];       // t coords (x,y)
  float2 jc2[128];       // j coords (x,y)
};                       // 34,816 B -> 4 blocks/CU

__global__ __launch_bounds__(256, 4)
void k_mfma_argmax(const unsigned char* __restrict__ tarQ,
                   const unsigned char* __restrict__ refQ,
                   const float* __restrict__ un, const int* __restrict__ relax,
                   uint2* __restrict__ partial) {
  __shared__ Smem sm;
  const int tid = threadIdx.x;
  const int lane = tid & 63;
  const int wid = tid >> 6;

  // XCD swizzle (5776 % 8 == 0)
  const int bid = blockIdx.x;
  const int item = (bid & 7) * (NBLK / 8) + (bid >> 3);
  const int b = item / (NTJ * NTT);
  const int r2 = item - b * (NTJ * NTT);
  const int jt = r2 / NTT, tt = r2 % NTT;
  const int tbase = tt * BT, jbase = jt * BJ;
  const float* unb = un + (size_t)b * 2 * NP;

  // stage coords into LDS (before first barrier)
  if (tid < 128) {
    const int tg = (tbase + tid < NP) ? tbase + tid : NP - 1;
    sm.tc2[tid] = make_float2(unb[tg], unb[NP + tg]);
  } else {
    const int i2 = tid - 128;
    const int jg = (jbase + i2 < NP) ? jbase + i2 : NP - 1;
    sm.jc2[i2] = make_float2(unb[jg], unb[NP + jg]);
  }

  // staging: waves 0-1 -> A (64 rows each), waves 2-3 -> B (64 rows each)
  // global rows are 256 B (fp8, plain k); kb selects a 64-B slice.
  // Source slot pre-swizzled per qq: (l&3) ^ ((l>>3)&3) ^ qq  (row bits 1-2 and 4-5).
  const char* aSrc = (const char*)(tarQ + ((size_t)b * NPAD + tbase) * CDIM);
  const char* bSrc = (const char*)(refQ + ((size_t)b * NPAD + jbase) * CDIM);
  const char* gl; int ldsOff;
  if (wid < 2) {
    gl = aSrc + (size_t)(wid * 64 + (lane >> 2)) * 256;
    ldsOff = wid * 4096;
  } else {
    gl = bSrc + (size_t)((wid - 2) * 64 + (lane >> 2)) * 256;
    ldsOff = 8192 + (wid - 2) * 4096;
  }
  const int slotBase = (lane & 3) ^ ((lane >> 3) & 3);

#define STAGE(buf, kb) do { \
    char* ldst = sm.bufs[buf] + ldsOff; \
    const char* gsp = gl + (kb) * 64; \
    _Pragma("unroll") for (int qq = 0; qq < 4; ++qq) \
      GLD16(ldst + qq * 1024, gsp + (size_t)qq * 4096 + ((slotBase ^ qq) * 16)); \
  } while (0)

  const int wr = wid >> 1, wc = wid & 1;   // wave tile: 64t x 64j
  const int l31 = lane & 31, kg = lane >> 5;
  const int swm = ((l31 >> 1) & 3) ^ ((l31 >> 4) & 1);   // read-side slot swizzle (row bits 1-2, 4)

  f32x16 acc[2][2];
#pragma unroll
  for (int fa = 0; fa < 2; ++fa)
#pragma unroll
    for (int fb = 0; fb < 2; ++fb)
#pragma unroll
      for (int r = 0; r < 16; ++r) acc[fa][fb][r] = 0.f;

  // loop-invariant LDS read bases
  const char* aptr = sm.bufs[0] + (wr * 64 + l31) * 64;
  const char* bptr = sm.bufs[0] + 8192 + (wc * 64 + l31) * 64;

  STAGE(0, 0);
  __syncthreads();
#pragma unroll
  for (int kb = 0; kb < 4; ++kb) {   // K = 256 = 4 * 64
    const int bo = (kb & 1) * 16384;
    if (kb < 3) STAGE((kb & 1) ^ 1, kb + 1);   // issue next-tile loads before compute
    i32x8 aF[2], bF[2];
#pragma unroll
    for (int f = 0; f < 2; ++f) {
      const int sx0 = (((2 * kg) ^ swm ^ (f << 1)) << 4);      // f = row bit 5
      const int sx1 = (((2 * kg + 1) ^ swm ^ (f << 1)) << 4);
      const i32x4 alo = *(const i32x4*)(aptr + bo + f * 2048 + sx0);
      const i32x4 ahi = *(const i32x4*)(aptr + bo + f * 2048 + sx1);
      aF[f] = __builtin_shufflevector(alo, ahi, 0, 1, 2, 3, 4, 5, 6, 7);
      const i32x4 blo = *(const i32x4*)(bptr + bo + f * 2048 + sx0);
      const i32x4 bhi = *(const i32x4*)(bptr + bo + f * 2048 + sx1);
      bF[f] = __builtin_shufflevector(blo, bhi, 0, 1, 2, 3, 4, 5, 6, 7);
    }
    __builtin_amdgcn_s_setprio(1);
#pragma unroll
    for (int fa = 0; fa < 2; ++fa)
#pragma unroll
      for (int fb = 0; fb < 2; ++fb)
        acc[fa][fb] = __builtin_amdgcn_mfma_scale_f32_32x32x64_f8f6f4(
            aF[fa], bF[fb], acc[fa][fb], 0, 0,
            0, 0x7F7F7F7F, 0, 0x7F7F7F7F);   // fmt fp8/fp8, scales = 1.0
    __builtin_amdgcn_s_setprio(0);
    if (kb < 3) __syncthreads();   // kb3: no LDS reuse below (red is in bufs[0], reads ended kb2)
  }

  // ---- epilogue: packed-key dual argmax (u32: [31:13]=bits(acc+512), [12:0]=8191-t) ----
  const float rf = (float)relax[0];
  float jx[2], jy[2];
#pragma unroll
  for (int fb = 0; fb < 2; ++fb) {
    const float2 jj = sm.jc2[wc * 64 + fb * 32 + l31];
    jx[fb] = jj.x; jy[fb] = jj.y;
  }
  unsigned int kA[2] = {0u, 0u}, kI[2] = {0u, 0u};
  const unsigned int tinv0 = (unsigned int)(8191 - tbase);

#define EPILOG(TAIL) \
  _Pragma("unroll") for (int fa = 0; fa < 2; ++fa) { \
    _Pragma("unroll") for (int reg = 0; reg < 16; ++reg) { \
      const int tl = wr * 64 + fa * 32 + 4 * kg + (reg & 3) + 8 * (reg >> 2); \
      const float2 tj = sm.tc2[tl]; \
      const unsigned int tinv = tinv0 - tl; \
      _Pragma("unroll") for (int fb = 0; fb < 2; ++fb) { \
        unsigned int key = (__float_as_uint(acc[fa][fb][reg] + 512.f) & 0xFFFFE000u) | tinv; \
        if (TAIL && (tbase + tl >= NP)) key = 0u; \
        if (key > kA[fb]) kA[fb] = key; \
        const float mm = fmaxf(fabsf(tj.x - jx[fb]), fabsf(tj.y - jy[fb])); \
        const unsigned int keyI = (mm <= rf) ? 0u : key; \
        if (keyI > kI[fb]) kI[fb] = keyI; \
      } \
    } \
  }

  if (tbase + BT <= NP) { EPILOG(false) } else { EPILOG(true) }
#undef EPILOG

  // cross-lane reduce: lanes l and l^32 share j (disjoint t) -> one shfl step.
  uint2* red = (uint2*)sm.bufs[0];   // [2][128]; safe: bufs[0] reads ended at kb=2 barrier
#pragma unroll
  for (int fb = 0; fb < 2; ++fb) {
    const unsigned int oA = __shfl_xor(kA[fb], 32);
    const unsigned int oI = __shfl_xor(kI[fb], 32);
    if (oA > kA[fb]) kA[fb] = oA;
    if (oI > kI[fb]) kI[fb] = oI;
    if (kg == 0) red[wr * 128 + wc * 64 + fb * 32 + l31] = make_uint2(kA[fb], kI[fb]);
  }
  __syncthreads();
  if (tid < 128) {
    const int jg = jbase + tid;
    if (jg < NP) {
      uint2 p0 = red[tid];
      const uint2 p1 = red[128 + tid];
      if (p1.x > p0.x) p0.x = p1.x;
      if (p1.y > p0.y) p0.y = p1.y;
      partial[((size_t)b * NP + jg) * NTT + tt] = p0;
    }
  }
#undef STAGE
}

// ---------------- fused combine + loss + recall: 2 points/wave, block partials ----------------
// k_loss FIX retained (round 16): NTT=38 > 32 lanes — each lane also covers partial
// l+32 (rounds 14-15 silently dropped t-tiles 32-37).
__global__ __launch_bounds__(256)
void k_loss(const unsigned short* __restrict__ refB, const unsigned short* __restrict__ tarB,
            const float* __restrict__ un, const uint2* __restrict__ partial,
            float2* __restrict__ blockpart) {
  const int pg = threadIdx.x >> 5, l = threadIdx.x & 31;
  const int n = blockIdx.x * 8 + pg;
  const int b = blockIdx.y;
  const int bn = b * NP + n;
  unsigned int kA = 0u, kI = 0u;
  {
    const uint2 p = partial[(size_t)bn * NTT + l];          // l < 32 <= NTT
    kA = p.x; kI = p.y;
    if (l + 32 < NTT) {
      const uint2 q = partial[(size_t)bn * NTT + l + 32];
      if (q.x > kA) kA = q.x;
      if (q.y > kI) kI = q.y;
    }
  }
#pragma unroll
  for (int d = 1; d < 32; d <<= 1) {   // stays within the 32-lane group
    const unsigned int oA = __shfl_xor(kA, d);
    const unsigned int oI = __shfl_xor(kI, d);
    if (oA > kA) kA = oA;
    if (oI > kI) kI = oI;
  }
  const int nn  = 8191 - (int)(kA & 0x1FFFu);
  const int neg = 8191 - (int)(kI & 0x1FFFu);
  const int c0 = l * 8;
  const u16x8 rv = *(const u16x8*)(refB + ((size_t)b * NPAD + n) * CDIM + c0);
  const u16x8 tv = *(const u16x8*)(tarB + ((size_t)b * NPAD + n) * CDIM + c0);
  const u16x8 gv = *(const u16x8*)(tarB + ((size_t)b * NPAD + neg) * CDIM + c0);
  float dp = 0.f, dn = 0.f;
#pragma unroll
  for (int k = 0; k < 8; ++k) {
    const float r = bf2f(rv[k]);
    float d1 = r - bf2f(tv[k]) + 1e-6f;
    float d2 = r - bf2f(gv[k]) + 1e-6f;
    dp += d1 * d1;
    dn += d2 * d2;
  }
#pragma unroll
  for (int off = 1; off < 32; off <<= 1) {
    dp += __shfl_xor(dp, off);
    dn += __shfl_xor(dn, off);
  }
  __shared__ float2 sred[8];
  if (l == 0) {
    const float loss = fmaxf(sqrtf(dp) - sqrtf(dn) + 0.2f, 0.f);
    const float* unb = un + (size_t)b * 2 * NP;
    const float rec = (unb[nn] == unb[n] && unb[NP + nn] == unb[NP + n]) ? 1.f : 0.f;
    sred[pg] = make_float2(loss, rec);
  }
  __syncthreads();
  if (threadIdx.x == 0) {
    float sl = 0.f, sr = 0.f;
#pragma unroll
    for (int g = 0; g < 8; ++g) { sl += sred[g].x; sr += sred[g].y; }
    blockpart[b * NLB + blockIdx.x] = make_float2(sl, sr);
  }
}

// ---------------- final deterministic reduce (19.2 KB input) ----------------
__global__ __launch_bounds__(256)
void k_finalize(const float2* __restrict__ blockpart, float* __restrict__ out) {
  __shared__ float l[256], rr[256];
  float ls = 0.f, rs = 0.f;
  for (int i = threadIdx.x; i < BQ * NLB; i += 256) {
    const float2 p = blockpart[i];
    ls += p.x; rs += p.y;
  }
  l[threadIdx.x] = ls;
  rr[threadIdx.x] = rs;
  __syncthreads();
  for (int s = 128; s > 0; s >>= 1) {
    if (threadIdx.x < s) { l[threadIdx.x] += l[threadIdx.x + s]; rr[threadIdx.x] += rr[threadIdx.x + s]; }
    __syncthreads();
  }
  if (threadIdx.x == 0) {
    out[0] = l[0] / (float)(BQ * NP);
    out[1] = rr[0] / (float)(BQ * NP);
  }
}

extern "C" void kernel_launch(void* const* d_in, const int* in_sizes, int n_in,
                              void* d_out, int out_size, void* d_ws, size_t ws_size,
                              hipStream_t stream) {
  const float* src  = (const float*)d_in[0];
  const float* tgt  = (const float*)d_in[1];
  const float* spts = (const float*)d_in[2];
  const float* tpts = (const float*)d_in[3];
  const float* un   = (const float*)d_in[4];
  const int* relax  = (const int*)d_in[5];

  char* ws = (char*)d_ws;
  unsigned short* desT      = (unsigned short*)(ws + WS_DEST);
  uint2*          partial   = (uint2*)(ws + WS_PART);   // aliases desT (dead by then)
  unsigned short* refB      = (unsigned short*)(ws + WS_REFB);
  unsigned short* tarB      = (unsigned short*)(ws + WS_TARB);
  unsigned char*  refQ      = (unsigned char*)(ws + WS_REFQ);
  unsigned char*  tarQ      = (unsigned char*)(ws + WS_TARQ);
  float2*         blockpart = (float2*)(ws + WS_BPART);
  float*          out       = (float*)d_out;

  k_transpose<<<dim3(NP / 32, CDIM / 64, 8), dim3(32, 8), 0, stream>>>(src, tgt, desT);
  k_sample<<<dim3(NPAD / 8, BQ, 2), 256, 0, stream>>>(desT, spts, tpts, refB, tarB, refQ, tarQ);
  k_mfma_argmax<<<NBLK, 256, 0, stream>>>(tarQ, refQ, un, relax, partial);
  k_loss<<<dim3(NLB, BQ), 256, 0, stream>>>(refB, tarB, un, partial, blockpart);
  k_finalize<<<1, 256, 0, stream>>>(blockpart, out);
}